// Round 2
// baseline (1749.043 us; speedup 1.0000x reference)
//
#include <hip/hip_runtime.h>
#include <hip/hip_bf16.h>
#include <stdint.h>

#define BB 2
#define SS 192
#define DD 256
#define NROW (BB * SS)   // 384
#define NE (NROW * DD)   // 98304

// ---------------- threefry2x32-20 (Random123 / JAX, partitionable) ----------------
__device__ __forceinline__ uint32_t rotl32(uint32_t v, int d) {
  return (v << d) | (v >> (32 - d));
}

__device__ inline void threefry2x32(uint32_t k0, uint32_t k1, uint32_t x0, uint32_t x1,
                                    uint32_t* o0, uint32_t* o1) {
  uint32_t ks2 = k0 ^ k1 ^ 0x1BD11BDAu;
  x0 += k0; x1 += k1;
  const int ra[4] = {13, 15, 26, 6};
  const int rb[4] = {17, 29, 16, 24};
#pragma unroll
  for (int i = 0; i < 4; i++) { x0 += x1; x1 = rotl32(x1, ra[i]); x1 ^= x0; }
  x0 += k1; x1 += ks2 + 1u;
#pragma unroll
  for (int i = 0; i < 4; i++) { x0 += x1; x1 = rotl32(x1, rb[i]); x1 ^= x0; }
  x0 += ks2; x1 += k0 + 2u;
#pragma unroll
  for (int i = 0; i < 4; i++) { x0 += x1; x1 = rotl32(x1, ra[i]); x1 ^= x0; }
  x0 += k0; x1 += k1 + 3u;
#pragma unroll
  for (int i = 0; i < 4; i++) { x0 += x1; x1 = rotl32(x1, rb[i]); x1 ^= x0; }
  x0 += k1; x1 += ks2 + 4u;
#pragma unroll
  for (int i = 0; i < 4; i++) { x0 += x1; x1 = rotl32(x1, ra[i]); x1 ^= x0; }
  x0 += ks2; x1 += k0 + 5u;
  *o0 = x0; *o1 = x1;
}

__device__ inline float erfinv_xla_f32(float x) {
  float w = -log1pf(-x * x);
  float p;
  if (w < 5.0f) {
    w = w - 2.5f;
    p = 2.81022636e-08f;
    p = 3.43273939e-07f + p * w;
    p = -3.5233877e-06f + p * w;
    p = -4.39150654e-06f + p * w;
    p = 0.00021858087f + p * w;
    p = -0.00125372503f + p * w;
    p = -0.00417768164f + p * w;
    p = 0.246640727f + p * w;
    p = 1.50140941f + p * w;
  } else {
    w = sqrtf(w) - 3.0f;
    p = -0.000200214257f;
    p = 0.000100950558f + p * w;
    p = 0.00134934322f + p * w;
    p = -0.00367342844f + p * w;
    p = 0.00573950773f + p * w;
    p = -0.0076224613f + p * w;
    p = 0.00943887047f + p * w;
    p = 1.00167406f + p * w;
    p = 2.83297682f + p * w;
  }
  return p * x;
}

__device__ inline float jax_normal_from_bits(uint32_t bits) {
  float f = __uint_as_float((bits >> 9) | 0x3f800000u) - 1.0f;
  const float lo = -0.99999994f;  // nextafter(-1, 0)
  float u = f * (1.0f - lo) + lo;
  u = fmaxf(lo, u);
  return 1.4142135623730951f * erfinv_xla_f32(u);
}

// draw normal(key=(ka,kb), counter=(0,i)) the partitionable-threefry way
__device__ inline float jax_normal_at(uint32_t ka, uint32_t kb, uint32_t i) {
  uint32_t o0, o1;
  threefry2x32(ka, kb, 0u, i, &o0, &o1);
  return jax_normal_from_bits(o0 ^ o1);
}

// ---------------- reductions (256 threads = 4 waves of 64) ----------------
__device__ inline double blockSum(double v, double* red, int tid) {
#pragma unroll
  for (int o = 32; o > 0; o >>= 1) v += __shfl_down(v, o, 64);
  __syncthreads();
  if ((tid & 63) == 0) red[tid >> 6] = v;
  __syncthreads();
  return (red[0] + red[1]) + (red[2] + red[3]);
}

__device__ inline double reduceS_sum(const double* arr, double* red, int tid) {
  __syncthreads();
  if (tid < 64) {
    double v = arr[tid] + arr[tid + 64] + arr[tid + 128];
#pragma unroll
    for (int o = 32; o > 0; o >>= 1) v += __shfl_down(v, o, 64);
    if (tid == 0) red[4] = v;
  }
  __syncthreads();
  return red[4];
}

__device__ inline double reduceS_min(const double* arr, double* red, int tid) {
  __syncthreads();
  if (tid < 64) {
    double v = fmin(arr[tid], fmin(arr[tid + 64], arr[tid + 128]));
#pragma unroll
    for (int o = 32; o > 0; o >>= 1) v = fmin(v, __shfl_down(v, o, 64));
    if (tid == 0) red[5] = v;
  }
  __syncthreads();
  return red[5];
}

// per-s dot over d: vecLds[d] . khT[d*SS + tid], 16 independent accumulators
#define SDOT(vecLds, khTp, outv)                                             \
  {                                                                          \
    const float* cb_ = (khTp) + tid;                                         \
    double a_[16];                                                           \
    _Pragma("unroll") for (int u = 0; u < 16; ++u) a_[u] = 0.0;              \
    for (int d0 = 0; d0 < DD; d0 += 16) {                                    \
      _Pragma("unroll") for (int u = 0; u < 16; ++u)                         \
        a_[u] += (vecLds)[d0 + u] * (double)cb_[(size_t)(d0 + u) * SS];      \
    }                                                                        \
    _Pragma("unroll") for (int st = 8; st; st >>= 1)                         \
      _Pragma("unroll") for (int u = 0; u < st; ++u) a_[u] += a_[u + st];    \
    (outv) = a_[0];                                                          \
  }

// d-mapped weighted sum over s: sum_s wArr[s] * mat[s*DD + tid]
#define DSUM(wArr, mat, outv)                                                \
  {                                                                          \
    double a_[16];                                                           \
    _Pragma("unroll") for (int u = 0; u < 16; ++u) a_[u] = 0.0;              \
    for (int s0 = 0; s0 < SS; s0 += 16) {                                    \
      _Pragma("unroll") for (int u = 0; u < 16; ++u)                         \
        a_[u] += (wArr)[s0 + u] * (double)(mat)[(size_t)(s0 + u) * DD + tid];\
    }                                                                        \
    _Pragma("unroll") for (int st = 8; st; st >>= 1)                         \
      _Pragma("unroll") for (int u = 0; u < st; ++u) a_[u] += a_[u + st];    \
    (outv) = a_[0];                                                          \
  }

// ---------------- W transpose ----------------
__global__ void transpose4(const float* __restrict__ Wq, const float* __restrict__ Wk,
                           const float* __restrict__ Wv, const float* __restrict__ Wo,
                           float* __restrict__ WqT, float* __restrict__ WkT,
                           float* __restrict__ WvT, float* __restrict__ WoT) {
  int m = blockIdx.x >> 8;
  int i = blockIdx.x & 255;
  int j = threadIdx.x;
  const float* S_; float* D_;
  if (m == 0) { S_ = Wq; D_ = WqT; }
  else if (m == 1) { S_ = Wk; D_ = WkT; }
  else if (m == 2) { S_ = Wv; D_ = WvT; }
  else { S_ = Wo; D_ = WoT; }
  D_[i * DD + j] = S_[j * DD + i];
}

// ---------------- fused QKV projection + expmap0 rows ----------------
__global__ __launch_bounds__(256) void proj_kernel(
    const float* __restrict__ q_in, const float* __restrict__ k_in, const float* __restrict__ v_in,
    const float* __restrict__ WqT, const float* __restrict__ WkT, const float* __restrict__ WvT,
    const float* __restrict__ bq, const float* __restrict__ bk, const float* __restrict__ bv,
    float* __restrict__ qh, float* __restrict__ kb, float* __restrict__ vb,
    float* __restrict__ kh, float* __restrict__ khT, double* __restrict__ y2g) {
  const int row = blockIdx.x, m = blockIdx.y, j = threadIdx.x;
  __shared__ float xs[DD];
  __shared__ double red[8];
  const float* x; const float* WT; const float* bias;
  if (m == 0) { x = q_in; WT = WqT; bias = bq; }
  else if (m == 1) { x = k_in; WT = WkT; bias = bk; }
  else { x = v_in; WT = WvT; bias = bv; }
  xs[j] = x[(size_t)row * DD + j];
  __syncthreads();
  double a[16];
#pragma unroll
  for (int u = 0; u < 16; ++u) a[u] = 0.0;
  for (int i0 = 0; i0 < DD; i0 += 16) {
#pragma unroll
    for (int u = 0; u < 16; ++u)
      a[u] += (double)xs[i0 + u] * (double)WT[(size_t)(i0 + u) * DD + j];
  }
#pragma unroll
  for (int st = 8; st; st >>= 1)
#pragma unroll
    for (int u = 0; u < st; ++u) a[u] += a[u + st];
  double val = a[0] + (double)bias[j];

  if (m == 2) { vb[(size_t)row * DD + j] = (float)val; return; }

  double n2 = blockSum(val * val, red, j);
  double n = sqrt(n2);
  double cf = fmin(4.0 / (n + 1e-8), 1.0);
  double ncl = fmax(n * cf, 1e-15);
  double sc = tanh(ncl) * cf / ncl;
  if (m == 0) {
    qh[(size_t)row * DD + j] = (float)(val * sc);
  } else {
    kb[(size_t)row * DD + j] = (float)val;
    float khf = (float)(val * sc);
    kh[(size_t)row * DD + j] = khf;
    int bb = row / SS, s = row % SS;
    khT[((size_t)bb * DD + j) * SS + s] = khf;
    double y2 = blockSum((double)khf * (double)khf, red, j);
    if (j == 0) y2g[row] = y2;
  }
}

__global__ __launch_bounds__(256) void gemm_out(
    const float* __restrict__ hf, const float* __restrict__ WoT,
    const float* __restrict__ bo, float* __restrict__ out) {
  int row = blockIdx.x;
  int j = threadIdx.x;
  __shared__ float xs[DD];
  xs[j] = hf[(size_t)row * DD + j];
  __syncthreads();
  double a[16];
#pragma unroll
  for (int u = 0; u < 16; ++u) a[u] = 0.0;
  for (int i0 = 0; i0 < DD; i0 += 16) {
#pragma unroll
    for (int u = 0; u < 16; ++u)
      a[u] += (double)xs[i0 + u] * (double)WoT[(size_t)(i0 + u) * DD + j];
  }
#pragma unroll
  for (int st = 8; st; st >>= 1)
#pragma unroll
    for (int u = 0; u < st; ++u) a[u] += a[u + st];
  out[(size_t)row * DD + j] = (float)(a[0] + (double)bo[j]);
}

// ---------------- main fused per-(b,q) kernel ----------------
__global__ __launch_bounds__(256) void resonance_main(
    const float* __restrict__ q_hyp, const float* __restrict__ k_hyp,
    const float* __restrict__ k_hypT, const float* __restrict__ kmat,
    const float* __restrict__ vmat, const double* __restrict__ y2g,
    const float* __restrict__ tau_p, const float* __restrict__ ts_p,
    float* __restrict__ hfused) {
  __shared__ double xq[DD], xc[DD], vr[DD];
  __shared__ double y2s[SS], wun[SS], wns[SS], alf[SS], bet[SS], sA[SS], sB[SS];
  __shared__ double red[8];
  const int tid = threadIdx.x;
  const int blk = blockIdx.x;
  const int b = blk / SS;
  const size_t rowOff = (size_t)blk * DD;
  const float* khB = k_hyp + (size_t)b * SS * DD;
  const float* khT = k_hypT + (size_t)b * DD * SS;
  const float* kB = kmat + (size_t)b * SS * DD;
  const float* vB = vmat + (size_t)b * SS * DD;

  // inline JAX PRNG: nk = split(key(42), 3), partitionable scheme
  uint32_t nk0a, nk0b, nk1a, nk1b, nk2a, nk2b;
  threefry2x32(0u, 42u, 0u, 0u, &nk0a, &nk0b);
  threefry2x32(0u, 42u, 0u, 1u, &nk1a, &nk1b);
  threefry2x32(0u, 42u, 0u, 2u, &nk2a, &nk2b);
  const uint32_t ei = (uint32_t)(rowOff + tid);
  const double noiseval = 1e-5 * (double)jax_normal_at(nk0a, nk0b, ei);
  const double vrndval = (double)jax_normal_at(nk1a, nk1b, ei);
  const double odeval = 1e-4 * (double)jax_normal_at(nk2a, nk2b, (uint32_t)blk);

  double xqv = (double)q_hyp[rowOff + tid];
  xq[tid] = xqv;
  if (tid < SS) y2s[tid] = y2g[b * SS + tid];
  double x2q = blockSum(xqv * xqv, red, tid);  // syncs cover xq/y2s writes

  // ---- pairwise hyperbolic distance row ----
  if (tid < SS) {
    double dot;
    SDOT(xq, khT, dot);
    double y2 = y2s[tid];
    double A = 1.0 - 2.0 * dot + y2;
    double Dn = fmax(1.0 - 2.0 * dot + x2q * y2, 1e-15);
    double Bc = 1.0 - x2q;
    double u2 = (A * A * x2q - 2.0 * A * Bc * dot + Bc * Bc * y2) / (Dn * Dn);
    double unr = sqrt(fmax(u2, 0.0));
    sA[tid] = 2.0 * atanh(fmin(unr, 1.0 - 1e-7));
  }
  double mind = reduceS_min(sA, red, tid);
  if (tid < SS) wun[tid] = exp(-(sA[tid] - mind));
  double wsum = reduceS_sum(wun, red, tid);
  if (tid < SS) wns[tid] = wun[tid] * (1.0 / (wsum + 1e-8));
  __syncthreads();

  // ---- fused: h = wns.v and mu_raw = wns.k ----
  double hreg, mu;
  {
    double ha[8], ma[8];
#pragma unroll
    for (int u = 0; u < 8; ++u) { ha[u] = 0.0; ma[u] = 0.0; }
    for (int s0 = 0; s0 < SS; s0 += 8) {
#pragma unroll
      for (int u = 0; u < 8; ++u) {
        double w = wns[s0 + u];
        ha[u] += w * (double)vB[(size_t)(s0 + u) * DD + tid];
        ma[u] += w * (double)kB[(size_t)(s0 + u) * DD + tid];
      }
    }
#pragma unroll
    for (int st = 4; st; st >>= 1)
#pragma unroll
      for (int u = 0; u < st; ++u) { ha[u] += ha[u + st]; ma[u] += ma[u + st]; }
    hreg = ha[0]; mu = ma[0];
  }

  // ---- mu0 = expmap0(clip_tangent(mu)) ----
  double x2c;
  {
    double n2 = blockSum(mu * mu, red, tid);
    double n = sqrt(n2);
    double cf = fmin(4.0 / (n + 1e-8), 1.0);
    double ncl = fmax(n * cf, 1e-15);
    double th = tanh(ncl);
    xc[tid] = mu * (th * cf / ncl);
    x2c = th * th;
  }
  __syncthreads();

  // ---- Karcher flow: 3 Riemannian SGD steps ----
  for (int it = 0; it < 3; ++it) {
    if (tid < SS) {
      double dot;
      SDOT(xc, khT, dot);
      double y2 = y2s[tid];
      double A = 1.0 - 2.0 * dot + y2;
      double Dn = fmax(1.0 - 2.0 * dot + x2c * y2, 1e-15);
      double Bc = 1.0 - x2c;
      double u2 = (A * A * x2c - 2.0 * A * Bc * dot + Bc * Bc * y2) / (Dn * Dn);
      double unr = sqrt(fmax(u2, 0.0));
      double un = fmax(unr, 1e-15);
      double coef = fmax(Bc, 1e-15) * atanh(fmin(un, 1.0 - 1e-7)) / un;
      double cs = wns[tid] * coef / Dn;
      sA[tid] = cs;
      sB[tid] = cs * A;
    }
    double S1 = reduceS_sum(sB, red, tid);   // syncs cover sA/sB writes
    double g;
    DSUM(sA, khB, g);
    double xold = xc[tid];
    double Bc = 1.0 - x2c;
    double vg = Bc * g - S1 * xold;           // v_grad[d]
    double nv2 = blockSum(vg * vg, red, tid);
    double nv = 0.1 * sqrt(nv2);
    double cf = fmin(4.0 / (nv + 1e-8), 1.0);
    double nw = fmax(nv * cf, 1e-15);
    double tsc = tanh(nw / fmax(Bc, 1e-15));
    double zco = tsc * 0.1 * cf / nw;
    double z = zco * vg;
    double xz = blockSum(xold * z, red, tid);
    double z2 = tsc * tsc;
    double den = fmax(1.0 + 2.0 * xz + x2c * z2, 1e-15);
    double xnew = ((1.0 + 2.0 * xz + z2) * xold + (1.0 - x2c) * z) / den;
    xc[tid] = xnew;
    x2c = blockSum(xnew * xnew, red, tid);    // syncs cover xc write
  }

  // ---- k_centroid = projx(mu + noise) ----
  {
    double cn = xc[tid] + noiseval;
    double n2 = blockSum(cn * cn, red, tid);
    double nn = sqrt(n2);
    if (nn > 1.0 - 1e-5) cn *= (1.0 - 1e-5) / fmax(nn, 1e-15);
    xc[tid] = cn;
    x2c = blockSum(cn * cn, red, tid);        // syncs cover xc write
  }

  // ---- c2k distances, entropy, variance; alf/bet for weighted_k ----
  if (tid < SS) {
    double dot;
    SDOT(xc, khT, dot);
    double y2 = y2s[tid];
    double A = 1.0 - 2.0 * dot + y2;
    double Dn = fmax(1.0 - 2.0 * dot + x2c * y2, 1e-15);
    double Bc = 1.0 - x2c;
    double u2 = (A * A * x2c - 2.0 * A * Bc * dot + Bc * Bc * y2) / (Dn * Dn);
    double unr = sqrt(fmax(u2, 0.0));
    double c2k = 2.0 * atanh(fmin(unr, 1.0 - 1e-7));
    sA[tid] = wns[tid] * c2k * c2k;
    sB[tid] = -wns[tid] * log(wns[tid] + 1e-8);
    double un = fmax(unr, 1e-15);
    double gl = fmax(Bc, 1e-15) * atanh(fmin(un, 1.0 - 1e-7)) / (un * Dn);
    double sq = sqrt(wun[tid] + 1e-8);
    alf[tid] = -sq * gl * A;
    bet[tid] = sq * gl * Bc;
  }
  double variance = reduceS_sum(sA, red, tid);
  double entropy = reduceS_sum(sB, red, tid);
  double tau = (double)tau_p[0];
  double tension = variance - tau * exp(entropy);

  // ---- power iteration on weighted_k (rank-structured) ----
  {
    double n2 = blockSum(vrndval * vrndval, red, tid);
    vr[tid] = vrndval / fmax(sqrt(n2), 1e-8);
  }
  for (int it = 0; it < 3; ++it) {
    double dxv = blockSum(xc[tid] * vr[tid], red, tid);  // syncs cover vr write
    if (tid < SS) {
      double dot;
      SDOT(vr, khT, dot);
      double pj = alf[tid] * dxv + bet[tid] * dot;
      sA[tid] = alf[tid] * pj;
      sB[tid] = bet[tid] * pj;
    }
    double T1 = reduceS_sum(sA, red, tid);
    double g;
    DSUM(sB, khB, g);
    double vnew = T1 * xc[tid] + g;
    double n2 = blockSum(vnew * vnew, red, tid);
    vr[tid] = vnew / fmax(sqrt(n2), 1e-8);
  }

  // ---- w_proj ----
  double wproj;
  {
    double wg = vr[tid] / fmax(1.0 - x2c, 1e-15);
    double nq = fmax(sqrt(x2q), 1e-15);
    double aq = atanh(fmin(nq, 1.0 - 1e-7)) / nq;
    double nc = fmax(sqrt(x2c), 1e-15);
    double ac = atanh(fmin(nc, 1.0 - 1e-7)) / nc;
    double f = aq * xq[tid] - ac * xc[tid];
    double n2 = blockSum(f * f, red, tid);
    double fb = f / fmax(sqrt(n2), 1e-8);
    wproj = (variance > 1e-5) ? wg : fb;
  }

  // ---- h_comp, x, pitchfork RK4 ----
  double hn2 = blockSum(hreg * hreg, red, tid);
  double hn = sqrt(hn2);
  double hsc = asinh(hn) / (hn + 1e-8);
  double hc = hsc * hreg;
  double x = blockSum(hc * wproj, red, tid);
  double xi = (x == 0.0) ? odeval : x;
  const double dt = 0.5;
#pragma unroll
  for (int r = 0; r < 4; ++r) {
    double k1 = dt * (tension * xi - xi * xi * xi);
    double a2 = xi + 0.5 * k1;
    double k2 = dt * (tension * a2 - a2 * a2 * a2);
    double a3 = xi + 0.5 * k2;
    double k3 = dt * (tension * a3 - a3 * a3 * a3);
    double a4 = xi + k3;
    double k4 = dt * (tension * a4 - a4 * a4 * a4);
    xi += (k1 + 2.0 * k2 + 2.0 * k3 + k4) / 6.0;
  }
  double ts = (double)ts_p[0];
  double hp = (hc + (xi - x) * wproj) * ts;
  double hp2 = blockSum(hp * hp, red, tid);
  double nhp = sqrt(hp2);
  double cf = fmin(4.0 / (nhp + 1e-8), 1.0);
  double ncl = fmax(nhp * cf, 1e-15);
  double th = tanh(ncl);
  double nb = fmax(th, 1e-15);
  double ab = atanh(fmin(nb, 1.0 - 1e-7)) / nb;
  double hob = ab * th * cf / ncl * hp;
  double gate = fmax(tanh(tension / fmax(tau, 1e-3)), 0.0);
  hfused[rowOff + tid] = (float)((1.0 - gate) * hreg + gate * hob);
}

// ---------------- launch ----------------
extern "C" void kernel_launch(void* const* d_in, const int* in_sizes, int n_in,
                              void* d_out, int out_size, void* d_ws, size_t ws_size,
                              hipStream_t stream) {
  const float* q_in = (const float*)d_in[0];
  const float* k_in = (const float*)d_in[1];
  const float* v_in = (const float*)d_in[2];
  const float* Wq = (const float*)d_in[3];
  const float* bq = (const float*)d_in[4];
  const float* Wk = (const float*)d_in[5];
  const float* bk = (const float*)d_in[6];
  const float* Wv = (const float*)d_in[7];
  const float* bv = (const float*)d_in[8];
  const float* Wo = (const float*)d_in[9];
  const float* bo = (const float*)d_in[10];
  const float* tau = (const float*)d_in[11];
  const float* ts = (const float*)d_in[12];
  float* out = (float*)d_out;
  (void)in_sizes; (void)n_in; (void)out_size; (void)ws_size;

  char* base = (char*)d_ws;
  size_t off = 0;
  auto alloc = [&](size_t bytes) -> void* {
    void* p = base + off;
    off += (bytes + 255) & ~(size_t)255;
    return p;
  };
  float* WqT = (float*)alloc((size_t)DD * DD * 4);
  float* WkT = (float*)alloc((size_t)DD * DD * 4);
  float* WvT = (float*)alloc((size_t)DD * DD * 4);
  float* WoT = (float*)alloc((size_t)DD * DD * 4);
  float* kb = (float*)alloc((size_t)NE * 4);
  float* vb = (float*)alloc((size_t)NE * 4);
  float* qh = (float*)alloc((size_t)NE * 4);
  float* kh = (float*)alloc((size_t)NE * 4);
  float* khT = (float*)alloc((size_t)NE * 4);
  double* y2g = (double*)alloc((size_t)NROW * 8);
  float* hf = (float*)alloc((size_t)NE * 4);

  hipLaunchKernelGGL(transpose4, dim3(4 * DD), dim3(DD), 0, stream,
                     Wq, Wk, Wv, Wo, WqT, WkT, WvT, WoT);
  hipLaunchKernelGGL(proj_kernel, dim3(NROW, 3), dim3(DD), 0, stream,
                     q_in, k_in, v_in, WqT, WkT, WvT, bq, bk, bv,
                     qh, kb, vb, kh, khT, y2g);
  hipLaunchKernelGGL(resonance_main, dim3(NROW), dim3(DD), 0, stream,
                     qh, kh, khT, kb, vb, y2g, tau, ts, hf);
  hipLaunchKernelGGL(gemm_out, dim3(NROW), dim3(DD), 0, stream, hf, WoT, bo, out);
}

// Round 3
// 1749.007 us; speedup vs baseline: 1.0000x; 1.0000x over previous
//
#include <hip/hip_runtime.h>
#include <hip/hip_bf16.h>
#include <stdint.h>

#define BB 2
#define SS 192
#define DD 256
#define NROW (BB * SS)   // 384
#define NE (NROW * DD)   // 98304

// ---------------- threefry2x32-20 (Random123 / JAX, partitionable) ----------------
__device__ __forceinline__ uint32_t rotl32(uint32_t v, int d) {
  return (v << d) | (v >> (32 - d));
}

__device__ inline void threefry2x32(uint32_t k0, uint32_t k1, uint32_t x0, uint32_t x1,
                                    uint32_t* o0, uint32_t* o1) {
  uint32_t ks2 = k0 ^ k1 ^ 0x1BD11BDAu;
  x0 += k0; x1 += k1;
  const int ra[4] = {13, 15, 26, 6};
  const int rb[4] = {17, 29, 16, 24};
#pragma unroll
  for (int i = 0; i < 4; i++) { x0 += x1; x1 = rotl32(x1, ra[i]); x1 ^= x0; }
  x0 += k1; x1 += ks2 + 1u;
#pragma unroll
  for (int i = 0; i < 4; i++) { x0 += x1; x1 = rotl32(x1, rb[i]); x1 ^= x0; }
  x0 += ks2; x1 += k0 + 2u;
#pragma unroll
  for (int i = 0; i < 4; i++) { x0 += x1; x1 = rotl32(x1, ra[i]); x1 ^= x0; }
  x0 += k0; x1 += k1 + 3u;
#pragma unroll
  for (int i = 0; i < 4; i++) { x0 += x1; x1 = rotl32(x1, rb[i]); x1 ^= x0; }
  x0 += k1; x1 += ks2 + 4u;
#pragma unroll
  for (int i = 0; i < 4; i++) { x0 += x1; x1 = rotl32(x1, ra[i]); x1 ^= x0; }
  x0 += ks2; x1 += k0 + 5u;
  *o0 = x0; *o1 = x1;
}

__device__ inline float erfinv_xla_f32(float x) {
  float w = -log1pf(-x * x);
  float p;
  if (w < 5.0f) {
    w = w - 2.5f;
    p = 2.81022636e-08f;
    p = 3.43273939e-07f + p * w;
    p = -3.5233877e-06f + p * w;
    p = -4.39150654e-06f + p * w;
    p = 0.00021858087f + p * w;
    p = -0.00125372503f + p * w;
    p = -0.00417768164f + p * w;
    p = 0.246640727f + p * w;
    p = 1.50140941f + p * w;
  } else {
    w = sqrtf(w) - 3.0f;
    p = -0.000200214257f;
    p = 0.000100950558f + p * w;
    p = 0.00134934322f + p * w;
    p = -0.00367342844f + p * w;
    p = 0.00573950773f + p * w;
    p = -0.0076224613f + p * w;
    p = 0.00943887047f + p * w;
    p = 1.00167406f + p * w;
    p = 2.83297682f + p * w;
  }
  return p * x;
}

__device__ inline float jax_normal_from_bits(uint32_t bits) {
  float f = __uint_as_float((bits >> 9) | 0x3f800000u) - 1.0f;
  const float lo = -0.99999994f;  // nextafter(-1, 0)
  float u = f * (1.0f - lo) + lo;
  u = fmaxf(lo, u);
  return 1.4142135623730951f * erfinv_xla_f32(u);
}

// draw normal(key=(ka,kb), counter=(0,i)) the partitionable-threefry way
__device__ inline float jax_normal_at(uint32_t ka, uint32_t kb, uint32_t i) {
  uint32_t o0, o1;
  threefry2x32(ka, kb, 0u, i, &o0, &o1);
  return jax_normal_from_bits(o0 ^ o1);
}

// ---------------- reductions (256 threads = 4 waves of 64) ----------------
__device__ inline double blockSum(double v, double* red, int tid) {
#pragma unroll
  for (int o = 32; o > 0; o >>= 1) v += __shfl_down(v, o, 64);
  __syncthreads();
  if ((tid & 63) == 0) red[tid >> 6] = v;
  __syncthreads();
  return (red[0] + red[1]) + (red[2] + red[3]);
}

__device__ inline double reduceS_sum(const double* arr, double* red, int tid) {
  __syncthreads();
  if (tid < 64) {
    double v = arr[tid] + arr[tid + 64] + arr[tid + 128];
#pragma unroll
    for (int o = 32; o > 0; o >>= 1) v += __shfl_down(v, o, 64);
    if (tid == 0) red[4] = v;
  }
  __syncthreads();
  return red[4];
}

__device__ inline double reduceS_min(const double* arr, double* red, int tid) {
  __syncthreads();
  if (tid < 64) {
    double v = fmin(arr[tid], fmin(arr[tid + 64], arr[tid + 128]));
#pragma unroll
    for (int o = 32; o > 0; o >>= 1) v = fmin(v, __shfl_down(v, o, 64));
    if (tid == 0) red[5] = v;
  }
  __syncthreads();
  return red[5];
}

// per-s dot over d: vecLds[d] . khT[d*SS + tid], 16 independent accumulators
#define SDOT(vecLds, khTp, outv)                                             \
  {                                                                          \
    const float* cb_ = (khTp) + tid;                                         \
    double a_[16];                                                           \
    _Pragma("unroll") for (int u = 0; u < 16; ++u) a_[u] = 0.0;              \
    for (int d0 = 0; d0 < DD; d0 += 16) {                                    \
      _Pragma("unroll") for (int u = 0; u < 16; ++u)                         \
        a_[u] += (vecLds)[d0 + u] * (double)cb_[(size_t)(d0 + u) * SS];      \
    }                                                                        \
    _Pragma("unroll") for (int st = 8; st; st >>= 1)                         \
      _Pragma("unroll") for (int u = 0; u < st; ++u) a_[u] += a_[u + st];    \
    (outv) = a_[0];                                                          \
  }

// d-mapped weighted sum over s: sum_s wArr[s] * mat[s*DD + tid]
#define DSUM(wArr, mat, outv)                                                \
  {                                                                          \
    double a_[16];                                                           \
    _Pragma("unroll") for (int u = 0; u < 16; ++u) a_[u] = 0.0;              \
    for (int s0 = 0; s0 < SS; s0 += 16) {                                    \
      _Pragma("unroll") for (int u = 0; u < 16; ++u)                         \
        a_[u] += (wArr)[s0 + u] * (double)(mat)[(size_t)(s0 + u) * DD + tid];\
    }                                                                        \
    _Pragma("unroll") for (int st = 8; st; st >>= 1)                         \
      _Pragma("unroll") for (int u = 0; u < st; ++u) a_[u] += a_[u + st];    \
    (outv) = a_[0];                                                          \
  }

// ---------------- W transpose ----------------
__global__ void transpose4(const float* __restrict__ Wq, const float* __restrict__ Wk,
                           const float* __restrict__ Wv, const float* __restrict__ Wo,
                           float* __restrict__ WqT, float* __restrict__ WkT,
                           float* __restrict__ WvT, float* __restrict__ WoT) {
  int m = blockIdx.x >> 8;
  int i = blockIdx.x & 255;
  int j = threadIdx.x;
  const float* S_; float* D_;
  if (m == 0) { S_ = Wq; D_ = WqT; }
  else if (m == 1) { S_ = Wk; D_ = WkT; }
  else if (m == 2) { S_ = Wv; D_ = WvT; }
  else { S_ = Wo; D_ = WoT; }
  D_[i * DD + j] = S_[j * DD + i];
}

// ---------------- fused QKV projection + expmap0 rows ----------------
__global__ __launch_bounds__(256) void proj_kernel(
    const float* __restrict__ q_in, const float* __restrict__ k_in, const float* __restrict__ v_in,
    const float* __restrict__ WqT, const float* __restrict__ WkT, const float* __restrict__ WvT,
    const float* __restrict__ bq, const float* __restrict__ bk, const float* __restrict__ bv,
    float* __restrict__ qh, float* __restrict__ kb, float* __restrict__ vb,
    float* __restrict__ kh, float* __restrict__ khT, double* __restrict__ y2g) {
  const int row = blockIdx.x, m = blockIdx.y, j = threadIdx.x;
  __shared__ float xs[DD];
  __shared__ double red[8];
  const float* x; const float* WT; const float* bias;
  if (m == 0) { x = q_in; WT = WqT; bias = bq; }
  else if (m == 1) { x = k_in; WT = WkT; bias = bk; }
  else { x = v_in; WT = WvT; bias = bv; }
  xs[j] = x[(size_t)row * DD + j];
  __syncthreads();
  double a[16];
#pragma unroll
  for (int u = 0; u < 16; ++u) a[u] = 0.0;
  for (int i0 = 0; i0 < DD; i0 += 16) {
#pragma unroll
    for (int u = 0; u < 16; ++u)
      a[u] += (double)xs[i0 + u] * (double)WT[(size_t)(i0 + u) * DD + j];
  }
#pragma unroll
  for (int st = 8; st; st >>= 1)
#pragma unroll
    for (int u = 0; u < st; ++u) a[u] += a[u + st];
  double val = a[0] + (double)bias[j];

  if (m == 2) { vb[(size_t)row * DD + j] = (float)val; return; }

  double n2 = blockSum(val * val, red, j);
  double n = sqrt(n2);
  double cf = fmin(4.0 / (n + 1e-8), 1.0);
  double ncl = fmax(n * cf, 1e-15);
  double sc = tanh(ncl) * cf / ncl;
  if (m == 0) {
    qh[(size_t)row * DD + j] = (float)(val * sc);
  } else {
    kb[(size_t)row * DD + j] = (float)val;
    float khf = (float)(val * sc);
    kh[(size_t)row * DD + j] = khf;
    int bb = row / SS, s = row % SS;
    khT[((size_t)bb * DD + j) * SS + s] = khf;
    double y2 = blockSum((double)khf * (double)khf, red, j);
    if (j == 0) y2g[row] = y2;
  }
}

__global__ __launch_bounds__(256) void gemm_out(
    const float* __restrict__ hf, const float* __restrict__ WoT,
    const float* __restrict__ bo, float* __restrict__ out) {
  int row = blockIdx.x;
  int j = threadIdx.x;
  __shared__ float xs[DD];
  xs[j] = hf[(size_t)row * DD + j];
  __syncthreads();
  double a[16];
#pragma unroll
  for (int u = 0; u < 16; ++u) a[u] = 0.0;
  for (int i0 = 0; i0 < DD; i0 += 16) {
#pragma unroll
    for (int u = 0; u < 16; ++u)
      a[u] += (double)xs[i0 + u] * (double)WoT[(size_t)(i0 + u) * DD + j];
  }
#pragma unroll
  for (int st = 8; st; st >>= 1)
#pragma unroll
    for (int u = 0; u < st; ++u) a[u] += a[u + st];
  out[(size_t)row * DD + j] = (float)(a[0] + (double)bo[j]);
}

// ---------------- main fused per-(b,q) kernel ----------------
__global__ __launch_bounds__(256) void resonance_main(
    const float* __restrict__ q_hyp, const float* __restrict__ k_hyp,
    const float* __restrict__ k_hypT, const float* __restrict__ kmat,
    const float* __restrict__ vmat, const double* __restrict__ y2g,
    const float* __restrict__ tau_p, const float* __restrict__ ts_p,
    float* __restrict__ hfused) {
  __shared__ double xq[DD], xc[DD], vr[DD];
  __shared__ double y2s[SS], wun[SS], wns[SS], alf[SS], bet[SS], sA[SS], sB[SS];
  __shared__ double red[8];
  const int tid = threadIdx.x;
  const int blk = blockIdx.x;
  const int b = blk / SS;
  const size_t rowOff = (size_t)blk * DD;
  const float* khB = k_hyp + (size_t)b * SS * DD;
  const float* khT = k_hypT + (size_t)b * DD * SS;
  const float* kB = kmat + (size_t)b * SS * DD;
  const float* vB = vmat + (size_t)b * SS * DD;

  // inline JAX PRNG: nk = split(key(42), 3), partitionable scheme
  uint32_t nk0a, nk0b, nk1a, nk1b, nk2a, nk2b;
  threefry2x32(0u, 42u, 0u, 0u, &nk0a, &nk0b);
  threefry2x32(0u, 42u, 0u, 1u, &nk1a, &nk1b);
  threefry2x32(0u, 42u, 0u, 2u, &nk2a, &nk2b);
  const uint32_t ei = (uint32_t)(rowOff + tid);
  const double noiseval = 1e-5 * (double)jax_normal_at(nk0a, nk0b, ei);
  const double vrndval = (double)jax_normal_at(nk1a, nk1b, ei);
  const double odeval = 1e-4 * (double)jax_normal_at(nk2a, nk2b, (uint32_t)blk);

  double xqv = (double)q_hyp[rowOff + tid];
  xq[tid] = xqv;
  if (tid < SS) y2s[tid] = y2g[b * SS + tid];
  double x2q = blockSum(xqv * xqv, red, tid);  // syncs cover xq/y2s writes

  // ---- pairwise hyperbolic distance row ----
  if (tid < SS) {
    double dot;
    SDOT(xq, khT, dot);
    double y2 = y2s[tid];
    double A = 1.0 - 2.0 * dot + y2;
    double Dn = fmax(1.0 - 2.0 * dot + x2q * y2, 1e-15);
    double Bc = 1.0 - x2q;
    double u2 = (A * A * x2q - 2.0 * A * Bc * dot + Bc * Bc * y2) / (Dn * Dn);
    double unr = sqrt(fmax(u2, 0.0));
    sA[tid] = 2.0 * atanh(fmin(unr, 1.0 - 1e-7));
  }
  double mind = reduceS_min(sA, red, tid);
  if (tid < SS) wun[tid] = exp(-(sA[tid] - mind));
  double wsum = reduceS_sum(wun, red, tid);
  if (tid < SS) wns[tid] = wun[tid] * (1.0 / (wsum + 1e-8));
  __syncthreads();

  // ---- fused: h = wns.v and mu_raw = wns.k ----
  double hreg, mu;
  {
    double ha[8], ma[8];
#pragma unroll
    for (int u = 0; u < 8; ++u) { ha[u] = 0.0; ma[u] = 0.0; }
    for (int s0 = 0; s0 < SS; s0 += 8) {
#pragma unroll
      for (int u = 0; u < 8; ++u) {
        double w = wns[s0 + u];
        ha[u] += w * (double)vB[(size_t)(s0 + u) * DD + tid];
        ma[u] += w * (double)kB[(size_t)(s0 + u) * DD + tid];
      }
    }
#pragma unroll
    for (int st = 4; st; st >>= 1)
#pragma unroll
      for (int u = 0; u < st; ++u) { ha[u] += ha[u + st]; ma[u] += ma[u + st]; }
    hreg = ha[0]; mu = ma[0];
  }

  // ---- mu0 = expmap0(clip_tangent(mu)) ----
  double x2c;
  {
    double n2 = blockSum(mu * mu, red, tid);
    double n = sqrt(n2);
    double cf = fmin(4.0 / (n + 1e-8), 1.0);
    double ncl = fmax(n * cf, 1e-15);
    double th = tanh(ncl);
    xc[tid] = mu * (th * cf / ncl);
    x2c = th * th;
  }
  __syncthreads();

  // ---- Karcher flow: 3 Riemannian SGD steps ----
  for (int it = 0; it < 3; ++it) {
    if (tid < SS) {
      double dot;
      SDOT(xc, khT, dot);
      double y2 = y2s[tid];
      double A = 1.0 - 2.0 * dot + y2;
      double Dn = fmax(1.0 - 2.0 * dot + x2c * y2, 1e-15);
      double Bc = 1.0 - x2c;
      double u2 = (A * A * x2c - 2.0 * A * Bc * dot + Bc * Bc * y2) / (Dn * Dn);
      double unr = sqrt(fmax(u2, 0.0));
      double un = fmax(unr, 1e-15);
      double coef = fmax(Bc, 1e-15) * atanh(fmin(un, 1.0 - 1e-7)) / un;
      double cs = wns[tid] * coef / Dn;
      sA[tid] = cs;
      sB[tid] = cs * A;
    }
    double S1 = reduceS_sum(sB, red, tid);   // syncs cover sA/sB writes
    double g;
    DSUM(sA, khB, g);
    double xold = xc[tid];
    double Bc = 1.0 - x2c;
    double vg = Bc * g - S1 * xold;           // v_grad[d]
    double nv2 = blockSum(vg * vg, red, tid);
    double nv = 0.1 * sqrt(nv2);
    double cf = fmin(4.0 / (nv + 1e-8), 1.0);
    double nw = fmax(nv * cf, 1e-15);
    double tsc = tanh(nw / fmax(Bc, 1e-15));
    double zco = tsc * 0.1 * cf / nw;
    double z = zco * vg;
    double xz = blockSum(xold * z, red, tid);
    double z2 = tsc * tsc;
    double den = fmax(1.0 + 2.0 * xz + x2c * z2, 1e-15);
    double xnew = ((1.0 + 2.0 * xz + z2) * xold + (1.0 - x2c) * z) / den;
    xc[tid] = xnew;
    x2c = blockSum(xnew * xnew, red, tid);    // syncs cover xc write
  }

  // ---- k_centroid = projx(mu + noise) ----
  {
    double cn = xc[tid] + noiseval;
    double n2 = blockSum(cn * cn, red, tid);
    double nn = sqrt(n2);
    if (nn > 1.0 - 1e-5) cn *= (1.0 - 1e-5) / fmax(nn, 1e-15);
    xc[tid] = cn;
    x2c = blockSum(cn * cn, red, tid);        // syncs cover xc write
  }

  // ---- c2k distances, entropy, variance; alf/bet for weighted_k ----
  if (tid < SS) {
    double dot;
    SDOT(xc, khT, dot);
    double y2 = y2s[tid];
    double A = 1.0 - 2.0 * dot + y2;
    double Dn = fmax(1.0 - 2.0 * dot + x2c * y2, 1e-15);
    double Bc = 1.0 - x2c;
    double u2 = (A * A * x2c - 2.0 * A * Bc * dot + Bc * Bc * y2) / (Dn * Dn);
    double unr = sqrt(fmax(u2, 0.0));
    double c2k = 2.0 * atanh(fmin(unr, 1.0 - 1e-7));
    sA[tid] = wns[tid] * c2k * c2k;
    sB[tid] = -wns[tid] * log(wns[tid] + 1e-8);
    double un = fmax(unr, 1e-15);
    double gl = fmax(Bc, 1e-15) * atanh(fmin(un, 1.0 - 1e-7)) / (un * Dn);
    double sq = sqrt(wun[tid] + 1e-8);
    alf[tid] = -sq * gl * A;
    bet[tid] = sq * gl * Bc;
  }
  double variance = reduceS_sum(sA, red, tid);
  double entropy = reduceS_sum(sB, red, tid);
  double tau = (double)tau_p[0];
  double tension = variance - tau * exp(entropy);

  // ---- power iteration on weighted_k (rank-structured) ----
  {
    double n2 = blockSum(vrndval * vrndval, red, tid);
    vr[tid] = vrndval / fmax(sqrt(n2), 1e-8);
  }
  for (int it = 0; it < 3; ++it) {
    double dxv = blockSum(xc[tid] * vr[tid], red, tid);  // syncs cover vr write
    if (tid < SS) {
      double dot;
      SDOT(vr, khT, dot);
      double pj = alf[tid] * dxv + bet[tid] * dot;
      sA[tid] = alf[tid] * pj;
      sB[tid] = bet[tid] * pj;
    }
    double T1 = reduceS_sum(sA, red, tid);
    double g;
    DSUM(sB, khB, g);
    double vnew = T1 * xc[tid] + g;
    double n2 = blockSum(vnew * vnew, red, tid);
    vr[tid] = vnew / fmax(sqrt(n2), 1e-8);
  }

  // ---- w_proj ----
  double wproj;
  {
    double wg = vr[tid] / fmax(1.0 - x2c, 1e-15);
    double nq = fmax(sqrt(x2q), 1e-15);
    double aq = atanh(fmin(nq, 1.0 - 1e-7)) / nq;
    double nc = fmax(sqrt(x2c), 1e-15);
    double ac = atanh(fmin(nc, 1.0 - 1e-7)) / nc;
    double f = aq * xq[tid] - ac * xc[tid];
    double n2 = blockSum(f * f, red, tid);
    double fb = f / fmax(sqrt(n2), 1e-8);
    wproj = (variance > 1e-5) ? wg : fb;
  }

  // ---- h_comp, x, pitchfork RK4 ----
  double hn2 = blockSum(hreg * hreg, red, tid);
  double hn = sqrt(hn2);
  double hsc = asinh(hn) / (hn + 1e-8);
  double hc = hsc * hreg;
  double x = blockSum(hc * wproj, red, tid);
  double xi = (x == 0.0) ? odeval : x;
  const double dt = 0.5;
#pragma unroll
  for (int r = 0; r < 4; ++r) {
    double k1 = dt * (tension * xi - xi * xi * xi);
    double a2 = xi + 0.5 * k1;
    double k2 = dt * (tension * a2 - a2 * a2 * a2);
    double a3 = xi + 0.5 * k2;
    double k3 = dt * (tension * a3 - a3 * a3 * a3);
    double a4 = xi + k3;
    double k4 = dt * (tension * a4 - a4 * a4 * a4);
    xi += (k1 + 2.0 * k2 + 2.0 * k3 + k4) / 6.0;
  }
  double ts = (double)ts_p[0];
  double hp = (hc + (xi - x) * wproj) * ts;
  double hp2 = blockSum(hp * hp, red, tid);
  double nhp = sqrt(hp2);
  double cf = fmin(4.0 / (nhp + 1e-8), 1.0);
  double ncl = fmax(nhp * cf, 1e-15);
  double th = tanh(ncl);
  double nb = fmax(th, 1e-15);
  double ab = atanh(fmin(nb, 1.0 - 1e-7)) / nb;
  double hob = ab * th * cf / ncl * hp;
  double gate = fmax(tanh(tension / fmax(tau, 1e-3)), 0.0);
  hfused[rowOff + tid] = (float)((1.0 - gate) * hreg + gate * hob);
}

// ---------------- launch ----------------
extern "C" void kernel_launch(void* const* d_in, const int* in_sizes, int n_in,
                              void* d_out, int out_size, void* d_ws, size_t ws_size,
                              hipStream_t stream) {
  const float* q_in = (const float*)d_in[0];
  const float* k_in = (const float*)d_in[1];
  const float* v_in = (const float*)d_in[2];
  const float* Wq = (const float*)d_in[3];
  const float* bq = (const float*)d_in[4];
  const float* Wk = (const float*)d_in[5];
  const float* bk = (const float*)d_in[6];
  const float* Wv = (const float*)d_in[7];
  const float* bv = (const float*)d_in[8];
  const float* Wo = (const float*)d_in[9];
  const float* bo = (const float*)d_in[10];
  const float* tau = (const float*)d_in[11];
  const float* ts = (const float*)d_in[12];
  float* out = (float*)d_out;
  (void)in_sizes; (void)n_in; (void)out_size; (void)ws_size;

  char* base = (char*)d_ws;
  size_t off = 0;
  auto alloc = [&](size_t bytes) -> void* {
    void* p = base + off;
    off += (bytes + 255) & ~(size_t)255;
    return p;
  };
  float* WqT = (float*)alloc((size_t)DD * DD * 4);
  float* WkT = (float*)alloc((size_t)DD * DD * 4);
  float* WvT = (float*)alloc((size_t)DD * DD * 4);
  float* WoT = (float*)alloc((size_t)DD * DD * 4);
  float* kb = (float*)alloc((size_t)NE * 4);
  float* vb = (float*)alloc((size_t)NE * 4);
  float* qh = (float*)alloc((size_t)NE * 4);
  float* kh = (float*)alloc((size_t)NE * 4);
  float* khT = (float*)alloc((size_t)NE * 4);
  double* y2g = (double*)alloc((size_t)NROW * 8);
  float* hf = (float*)alloc((size_t)NE * 4);

  hipLaunchKernelGGL(transpose4, dim3(4 * DD), dim3(DD), 0, stream,
                     Wq, Wk, Wv, Wo, WqT, WkT, WvT, WoT);
  hipLaunchKernelGGL(proj_kernel, dim3(NROW, 3), dim3(DD), 0, stream,
                     q_in, k_in, v_in, WqT, WkT, WvT, bq, bk, bv,
                     qh, kb, vb, kh, khT, y2g);
  hipLaunchKernelGGL(resonance_main, dim3(NROW), dim3(DD), 0, stream,
                     qh, kh, khT, kb, vb, y2g, tau, ts, hf);
  hipLaunchKernelGGL(gemm_out, dim3(NROW), dim3(DD), 0, stream, hf, WoT, bo, out);
}

// Round 4
// 146.254 us; speedup vs baseline: 11.9589x; 11.9587x over previous
//
#include <hip/hip_runtime.h>
#include <hip/hip_bf16.h>
#include <stdint.h>

#define BB 2
#define SS 192
#define DD 256
#define NROW (BB * SS)   // 384
#define NE (NROW * DD)   // 98304

// ---------------- threefry2x32-20 (Random123 / JAX, partitionable) ----------------
__device__ __forceinline__ uint32_t rotl32(uint32_t v, int d) {
  return (v << d) | (v >> (32 - d));
}

__device__ inline void threefry2x32(uint32_t k0, uint32_t k1, uint32_t x0, uint32_t x1,
                                    uint32_t* o0, uint32_t* o1) {
  uint32_t ks2 = k0 ^ k1 ^ 0x1BD11BDAu;
  x0 += k0; x1 += k1;
  const int ra[4] = {13, 15, 26, 6};
  const int rb[4] = {17, 29, 16, 24};
#pragma unroll
  for (int i = 0; i < 4; i++) { x0 += x1; x1 = rotl32(x1, ra[i]); x1 ^= x0; }
  x0 += k1; x1 += ks2 + 1u;
#pragma unroll
  for (int i = 0; i < 4; i++) { x0 += x1; x1 = rotl32(x1, rb[i]); x1 ^= x0; }
  x0 += ks2; x1 += k0 + 2u;
#pragma unroll
  for (int i = 0; i < 4; i++) { x0 += x1; x1 = rotl32(x1, ra[i]); x1 ^= x0; }
  x0 += k0; x1 += k1 + 3u;
#pragma unroll
  for (int i = 0; i < 4; i++) { x0 += x1; x1 = rotl32(x1, rb[i]); x1 ^= x0; }
  x0 += k1; x1 += ks2 + 4u;
#pragma unroll
  for (int i = 0; i < 4; i++) { x0 += x1; x1 = rotl32(x1, ra[i]); x1 ^= x0; }
  x0 += ks2; x1 += k0 + 5u;
  *o0 = x0; *o1 = x1;
}

__device__ inline float erfinv_xla_f32(float x) {
  float w = -log1pf(-x * x);
  float p;
  if (w < 5.0f) {
    w = w - 2.5f;
    p = 2.81022636e-08f;
    p = 3.43273939e-07f + p * w;
    p = -3.5233877e-06f + p * w;
    p = -4.39150654e-06f + p * w;
    p = 0.00021858087f + p * w;
    p = -0.00125372503f + p * w;
    p = -0.00417768164f + p * w;
    p = 0.246640727f + p * w;
    p = 1.50140941f + p * w;
  } else {
    w = sqrtf(w) - 3.0f;
    p = -0.000200214257f;
    p = 0.000100950558f + p * w;
    p = 0.00134934322f + p * w;
    p = -0.00367342844f + p * w;
    p = 0.00573950773f + p * w;
    p = -0.0076224613f + p * w;
    p = 0.00943887047f + p * w;
    p = 1.00167406f + p * w;
    p = 2.83297682f + p * w;
  }
  return p * x;
}

__device__ inline float jax_normal_from_bits(uint32_t bits) {
  float f = __uint_as_float((bits >> 9) | 0x3f800000u) - 1.0f;
  const float lo = -0.99999994f;  // nextafter(-1, 0)
  float u = f * (1.0f - lo) + lo;
  u = fmaxf(lo, u);
  return 1.4142135623730951f * erfinv_xla_f32(u);
}

__device__ inline float jax_normal_at(uint32_t ka, uint32_t kb, uint32_t i) {
  uint32_t o0, o1;
  threefry2x32(ka, kb, 0u, i, &o0, &o1);
  return jax_normal_from_bits(o0 ^ o1);
}

// ---------------- reductions (256 threads = 4 waves of 64) ----------------
__device__ inline double blockSum(double v, double* red, int tid) {
#pragma unroll
  for (int o = 32; o > 0; o >>= 1) v += __shfl_down(v, o, 64);
  __syncthreads();
  if ((tid & 63) == 0) red[tid >> 6] = v;
  __syncthreads();
  return (red[0] + red[1]) + (red[2] + red[3]);
}

__device__ inline double reduceS_sum(const double* arr, double* red, int tid) {
  __syncthreads();
  if (tid < 64) {
    double v = arr[tid] + arr[tid + 64] + arr[tid + 128];
#pragma unroll
    for (int o = 32; o > 0; o >>= 1) v += __shfl_down(v, o, 64);
    if (tid == 0) red[4] = v;
  }
  __syncthreads();
  return red[4];
}

__device__ inline double reduceS_min(const double* arr, double* red, int tid) {
  __syncthreads();
  if (tid < 64) {
    double v = fmin(arr[tid], fmin(arr[tid + 64], arr[tid + 128]));
#pragma unroll
    for (int o = 32; o > 0; o >>= 1) v = fmin(v, __shfl_down(v, o, 64));
    if (tid == 0) red[5] = v;
  }
  __syncthreads();
  return red[5];
}

// per-s dot over d (tid < SS): 8 NAMED f64 accumulators, loads staged in named floats
#define SDOT(vecLds, khTp, outv) do {                                        \
    const float* cb_ = (khTp) + tid;                                         \
    double s0_=0.0,s1_=0.0,s2_=0.0,s3_=0.0,s4_=0.0,s5_=0.0,s6_=0.0,s7_=0.0;  \
    for (int d0_ = 0; d0_ < DD; d0_ += 8) {                                  \
      float f0_ = cb_[(size_t)(d0_ + 0) * SS];                               \
      float f1_ = cb_[(size_t)(d0_ + 1) * SS];                               \
      float f2_ = cb_[(size_t)(d0_ + 2) * SS];                               \
      float f3_ = cb_[(size_t)(d0_ + 3) * SS];                               \
      float f4_ = cb_[(size_t)(d0_ + 4) * SS];                               \
      float f5_ = cb_[(size_t)(d0_ + 5) * SS];                               \
      float f6_ = cb_[(size_t)(d0_ + 6) * SS];                               \
      float f7_ = cb_[(size_t)(d0_ + 7) * SS];                               \
      s0_ += (vecLds)[d0_ + 0] * (double)f0_;                                \
      s1_ += (vecLds)[d0_ + 1] * (double)f1_;                                \
      s2_ += (vecLds)[d0_ + 2] * (double)f2_;                                \
      s3_ += (vecLds)[d0_ + 3] * (double)f3_;                                \
      s4_ += (vecLds)[d0_ + 4] * (double)f4_;                                \
      s5_ += (vecLds)[d0_ + 5] * (double)f5_;                                \
      s6_ += (vecLds)[d0_ + 6] * (double)f6_;                                \
      s7_ += (vecLds)[d0_ + 7] * (double)f7_;                                \
    }                                                                        \
    (outv) = ((s0_ + s1_) + (s2_ + s3_)) + ((s4_ + s5_) + (s6_ + s7_));      \
  } while (0)

// d-mapped weighted sum over s: sum_s wArr[s] * mat[s*DD + tid]
#define DSUM(wArr, mat, outv) do {                                           \
    const float* mb_ = (mat) + tid;                                          \
    double s0_=0.0,s1_=0.0,s2_=0.0,s3_=0.0,s4_=0.0,s5_=0.0,s6_=0.0,s7_=0.0;  \
    for (int t0_ = 0; t0_ < SS; t0_ += 8) {                                  \
      float f0_ = mb_[(size_t)(t0_ + 0) * DD];                               \
      float f1_ = mb_[(size_t)(t0_ + 1) * DD];                               \
      float f2_ = mb_[(size_t)(t0_ + 2) * DD];                               \
      float f3_ = mb_[(size_t)(t0_ + 3) * DD];                               \
      float f4_ = mb_[(size_t)(t0_ + 4) * DD];                               \
      float f5_ = mb_[(size_t)(t0_ + 5) * DD];                               \
      float f6_ = mb_[(size_t)(t0_ + 6) * DD];                               \
      float f7_ = mb_[(size_t)(t0_ + 7) * DD];                               \
      s0_ += (wArr)[t0_ + 0] * (double)f0_;                                  \
      s1_ += (wArr)[t0_ + 1] * (double)f1_;                                  \
      s2_ += (wArr)[t0_ + 2] * (double)f2_;                                  \
      s3_ += (wArr)[t0_ + 3] * (double)f3_;                                  \
      s4_ += (wArr)[t0_ + 4] * (double)f4_;                                  \
      s5_ += (wArr)[t0_ + 5] * (double)f5_;                                  \
      s6_ += (wArr)[t0_ + 6] * (double)f6_;                                  \
      s7_ += (wArr)[t0_ + 7] * (double)f7_;                                  \
    }                                                                        \
    (outv) = ((s0_ + s1_) + (s2_ + s3_)) + ((s4_ + s5_) + (s6_ + s7_));      \
  } while (0)

// ---------------- W transpose ----------------
__global__ void transpose4(const float* __restrict__ Wq, const float* __restrict__ Wk,
                           const float* __restrict__ Wv, const float* __restrict__ Wo,
                           float* __restrict__ WqT, float* __restrict__ WkT,
                           float* __restrict__ WvT, float* __restrict__ WoT) {
  int m = blockIdx.x >> 8;
  int i = blockIdx.x & 255;
  int j = threadIdx.x;
  const float* S_; float* D_;
  if (m == 0) { S_ = Wq; D_ = WqT; }
  else if (m == 1) { S_ = Wk; D_ = WkT; }
  else if (m == 2) { S_ = Wv; D_ = WvT; }
  else { S_ = Wo; D_ = WoT; }
  D_[i * DD + j] = S_[j * DD + i];
}

// dot of xs[LDS f32, len DD] with WT column j, 8 named f64 accumulators
__device__ inline double colDot(const float* __restrict__ xs,
                                const float* __restrict__ WT, int j) {
  const float* cb = WT + j;
  double s0=0.0,s1=0.0,s2=0.0,s3=0.0,s4=0.0,s5=0.0,s6=0.0,s7=0.0;
  for (int i0 = 0; i0 < DD; i0 += 8) {
    float f0 = cb[(size_t)(i0 + 0) * DD];
    float f1 = cb[(size_t)(i0 + 1) * DD];
    float f2 = cb[(size_t)(i0 + 2) * DD];
    float f3 = cb[(size_t)(i0 + 3) * DD];
    float f4 = cb[(size_t)(i0 + 4) * DD];
    float f5 = cb[(size_t)(i0 + 5) * DD];
    float f6 = cb[(size_t)(i0 + 6) * DD];
    float f7 = cb[(size_t)(i0 + 7) * DD];
    s0 += (double)xs[i0 + 0] * (double)f0;
    s1 += (double)xs[i0 + 1] * (double)f1;
    s2 += (double)xs[i0 + 2] * (double)f2;
    s3 += (double)xs[i0 + 3] * (double)f3;
    s4 += (double)xs[i0 + 4] * (double)f4;
    s5 += (double)xs[i0 + 5] * (double)f5;
    s6 += (double)xs[i0 + 6] * (double)f6;
    s7 += (double)xs[i0 + 7] * (double)f7;
  }
  return ((s0 + s1) + (s2 + s3)) + ((s4 + s5) + (s6 + s7));
}

// ---------------- fused QKV projection + expmap0 rows ----------------
__global__ __launch_bounds__(256) void proj_kernel(
    const float* __restrict__ q_in, const float* __restrict__ k_in, const float* __restrict__ v_in,
    const float* __restrict__ WqT, const float* __restrict__ WkT, const float* __restrict__ WvT,
    const float* __restrict__ bq, const float* __restrict__ bk, const float* __restrict__ bv,
    float* __restrict__ qh, float* __restrict__ kb, float* __restrict__ vb,
    float* __restrict__ kh, float* __restrict__ khT, double* __restrict__ y2g) {
  const int row = blockIdx.x, m = blockIdx.y, j = threadIdx.x;
  __shared__ float xs[DD];
  __shared__ double red[8];
  const float* x; const float* WT; const float* bias;
  if (m == 0) { x = q_in; WT = WqT; bias = bq; }
  else if (m == 1) { x = k_in; WT = WkT; bias = bk; }
  else { x = v_in; WT = WvT; bias = bv; }
  xs[j] = x[(size_t)row * DD + j];
  __syncthreads();
  double val = colDot(xs, WT, j) + (double)bias[j];

  if (m == 2) { vb[(size_t)row * DD + j] = (float)val; return; }

  double n2 = blockSum(val * val, red, j);
  double n = sqrt(n2);
  double cf = fmin(4.0 / (n + 1e-8), 1.0);
  double ncl = fmax(n * cf, 1e-15);
  double sc = tanh(ncl) * cf / ncl;
  if (m == 0) {
    qh[(size_t)row * DD + j] = (float)(val * sc);
  } else {
    kb[(size_t)row * DD + j] = (float)val;
    float khf = (float)(val * sc);
    kh[(size_t)row * DD + j] = khf;
    int bb = row / SS, s = row % SS;
    khT[((size_t)bb * DD + j) * SS + s] = khf;
    double y2 = blockSum((double)khf * (double)khf, red, j);
    if (j == 0) y2g[row] = y2;
  }
}

__global__ __launch_bounds__(256) void gemm_out(
    const float* __restrict__ hf, const float* __restrict__ WoT,
    const float* __restrict__ bo, float* __restrict__ out) {
  int row = blockIdx.x;
  int j = threadIdx.x;
  __shared__ float xs[DD];
  xs[j] = hf[(size_t)row * DD + j];
  __syncthreads();
  out[(size_t)row * DD + j] = (float)(colDot(xs, WoT, j) + (double)bo[j]);
}

// ---------------- main fused per-(b,q) kernel ----------------
__global__ __launch_bounds__(256) void resonance_main(
    const float* __restrict__ q_hyp, const float* __restrict__ k_hyp,
    const float* __restrict__ k_hypT, const float* __restrict__ kmat,
    const float* __restrict__ vmat, const double* __restrict__ y2g,
    const float* __restrict__ tau_p, const float* __restrict__ ts_p,
    float* __restrict__ hfused) {
  __shared__ double xq[DD], xc[DD], vr[DD];
  __shared__ double y2s[SS], wun[SS], wns[SS], alf[SS], bet[SS], sA[SS], sB[SS];
  __shared__ double red[8];
  const int tid = threadIdx.x;
  const int blk = blockIdx.x;
  const int b = blk / SS;
  const size_t rowOff = (size_t)blk * DD;
  const float* khB = k_hyp + (size_t)b * SS * DD;
  const float* khT = k_hypT + (size_t)b * DD * SS;
  const float* kB = kmat + (size_t)b * SS * DD;
  const float* vB = vmat + (size_t)b * SS * DD;

  // inline JAX PRNG: nk = split(key(42), 3), partitionable scheme
  uint32_t nk0a, nk0b, nk1a, nk1b, nk2a, nk2b;
  threefry2x32(0u, 42u, 0u, 0u, &nk0a, &nk0b);
  threefry2x32(0u, 42u, 0u, 1u, &nk1a, &nk1b);
  threefry2x32(0u, 42u, 0u, 2u, &nk2a, &nk2b);
  const uint32_t ei = (uint32_t)(rowOff + tid);
  const double noiseval = 1e-5 * (double)jax_normal_at(nk0a, nk0b, ei);
  const double vrndval = (double)jax_normal_at(nk1a, nk1b, ei);
  const double odeval = 1e-4 * (double)jax_normal_at(nk2a, nk2b, (uint32_t)blk);

  double xqv = (double)q_hyp[rowOff + tid];
  xq[tid] = xqv;
  if (tid < SS) y2s[tid] = y2g[b * SS + tid];
  double x2q = blockSum(xqv * xqv, red, tid);  // syncs cover xq/y2s writes

  // ---- pairwise hyperbolic distance row ----
  if (tid < SS) {
    double dot;
    SDOT(xq, khT, dot);
    double y2 = y2s[tid];
    double A = 1.0 - 2.0 * dot + y2;
    double Dn = fmax(1.0 - 2.0 * dot + x2q * y2, 1e-15);
    double Bc = 1.0 - x2q;
    double u2 = (A * A * x2q - 2.0 * A * Bc * dot + Bc * Bc * y2) / (Dn * Dn);
    double unr = sqrt(fmax(u2, 0.0));
    sA[tid] = 2.0 * atanh(fmin(unr, 1.0 - 1e-7));
  }
  double mind = reduceS_min(sA, red, tid);
  if (tid < SS) wun[tid] = exp(-(sA[tid] - mind));
  double wsum = reduceS_sum(wun, red, tid);
  if (tid < SS) wns[tid] = wun[tid] * (1.0 / (wsum + 1e-8));
  __syncthreads();

  // ---- fused: h = wns.v and mu_raw = wns.k (4+4 named accumulators) ----
  double hreg, mu;
  {
    const float* vb_ = vB + tid;
    const float* kb_ = kB + tid;
    double h0=0.0,h1=0.0,h2=0.0,h3=0.0, m0=0.0,m1=0.0,m2=0.0,m3=0.0;
    for (int s0 = 0; s0 < SS; s0 += 4) {
      float v0 = vb_[(size_t)(s0 + 0) * DD];
      float v1 = vb_[(size_t)(s0 + 1) * DD];
      float v2 = vb_[(size_t)(s0 + 2) * DD];
      float v3 = vb_[(size_t)(s0 + 3) * DD];
      float k0 = kb_[(size_t)(s0 + 0) * DD];
      float k1 = kb_[(size_t)(s0 + 1) * DD];
      float k2 = kb_[(size_t)(s0 + 2) * DD];
      float k3 = kb_[(size_t)(s0 + 3) * DD];
      double w0 = wns[s0 + 0], w1 = wns[s0 + 1], w2 = wns[s0 + 2], w3 = wns[s0 + 3];
      h0 += w0 * (double)v0; h1 += w1 * (double)v1;
      h2 += w2 * (double)v2; h3 += w3 * (double)v3;
      m0 += w0 * (double)k0; m1 += w1 * (double)k1;
      m2 += w2 * (double)k2; m3 += w3 * (double)k3;
    }
    hreg = (h0 + h1) + (h2 + h3);
    mu = (m0 + m1) + (m2 + m3);
  }

  // ---- mu0 = expmap0(clip_tangent(mu)) ----
  double x2c;
  {
    double n2 = blockSum(mu * mu, red, tid);
    double n = sqrt(n2);
    double cf = fmin(4.0 / (n + 1e-8), 1.0);
    double ncl = fmax(n * cf, 1e-15);
    double th = tanh(ncl);
    xc[tid] = mu * (th * cf / ncl);
    x2c = th * th;
  }
  __syncthreads();

  // ---- Karcher flow: 3 Riemannian SGD steps ----
  for (int it = 0; it < 3; ++it) {
    if (tid < SS) {
      double dot;
      SDOT(xc, khT, dot);
      double y2 = y2s[tid];
      double A = 1.0 - 2.0 * dot + y2;
      double Dn = fmax(1.0 - 2.0 * dot + x2c * y2, 1e-15);
      double Bc = 1.0 - x2c;
      double u2 = (A * A * x2c - 2.0 * A * Bc * dot + Bc * Bc * y2) / (Dn * Dn);
      double unr = sqrt(fmax(u2, 0.0));
      double un = fmax(unr, 1e-15);
      double coef = fmax(Bc, 1e-15) * atanh(fmin(un, 1.0 - 1e-7)) / un;
      double cs = wns[tid] * coef / Dn;
      sA[tid] = cs;
      sB[tid] = cs * A;
    }
    double S1 = reduceS_sum(sB, red, tid);   // syncs cover sA/sB writes
    double g;
    DSUM(sA, khB, g);
    double xold = xc[tid];
    double Bc = 1.0 - x2c;
    double vg = Bc * g - S1 * xold;           // v_grad[d]
    double nv2 = blockSum(vg * vg, red, tid);
    double nv = 0.1 * sqrt(nv2);
    double cf = fmin(4.0 / (nv + 1e-8), 1.0);
    double nw = fmax(nv * cf, 1e-15);
    double tsc = tanh(nw / fmax(Bc, 1e-15));
    double zco = tsc * 0.1 * cf / nw;
    double z = zco * vg;
    double xz = blockSum(xold * z, red, tid);
    double z2 = tsc * tsc;
    double den = fmax(1.0 + 2.0 * xz + x2c * z2, 1e-15);
    double xnew = ((1.0 + 2.0 * xz + z2) * xold + (1.0 - x2c) * z) / den;
    xc[tid] = xnew;
    x2c = blockSum(xnew * xnew, red, tid);    // syncs cover xc write
  }

  // ---- k_centroid = projx(mu + noise) ----
  {
    double cn = xc[tid] + noiseval;
    double n2 = blockSum(cn * cn, red, tid);
    double nn = sqrt(n2);
    if (nn > 1.0 - 1e-5) cn *= (1.0 - 1e-5) / fmax(nn, 1e-15);
    xc[tid] = cn;
    x2c = blockSum(cn * cn, red, tid);        // syncs cover xc write
  }

  // ---- c2k distances, entropy, variance; alf/bet for weighted_k ----
  if (tid < SS) {
    double dot;
    SDOT(xc, khT, dot);
    double y2 = y2s[tid];
    double A = 1.0 - 2.0 * dot + y2;
    double Dn = fmax(1.0 - 2.0 * dot + x2c * y2, 1e-15);
    double Bc = 1.0 - x2c;
    double u2 = (A * A * x2c - 2.0 * A * Bc * dot + Bc * Bc * y2) / (Dn * Dn);
    double unr = sqrt(fmax(u2, 0.0));
    double c2k = 2.0 * atanh(fmin(unr, 1.0 - 1e-7));
    sA[tid] = wns[tid] * c2k * c2k;
    sB[tid] = -wns[tid] * log(wns[tid] + 1e-8);
    double un = fmax(unr, 1e-15);
    double gl = fmax(Bc, 1e-15) * atanh(fmin(un, 1.0 - 1e-7)) / (un * Dn);
    double sq = sqrt(wun[tid] + 1e-8);
    alf[tid] = -sq * gl * A;
    bet[tid] = sq * gl * Bc;
  }
  double variance = reduceS_sum(sA, red, tid);
  double entropy = reduceS_sum(sB, red, tid);
  double tau = (double)tau_p[0];
  double tension = variance - tau * exp(entropy);

  // ---- power iteration on weighted_k (rank-structured) ----
  {
    double n2 = blockSum(vrndval * vrndval, red, tid);
    vr[tid] = vrndval / fmax(sqrt(n2), 1e-8);
  }
  for (int it = 0; it < 3; ++it) {
    double dxv = blockSum(xc[tid] * vr[tid], red, tid);  // syncs cover vr write
    if (tid < SS) {
      double dot;
      SDOT(vr, khT, dot);
      double pj = alf[tid] * dxv + bet[tid] * dot;
      sA[tid] = alf[tid] * pj;
      sB[tid] = bet[tid] * pj;
    }
    double T1 = reduceS_sum(sA, red, tid);
    double g;
    DSUM(sB, khB, g);
    double vnew = T1 * xc[tid] + g;
    double n2 = blockSum(vnew * vnew, red, tid);
    vr[tid] = vnew / fmax(sqrt(n2), 1e-8);
  }

  // ---- w_proj ----
  double wproj;
  {
    double wg = vr[tid] / fmax(1.0 - x2c, 1e-15);
    double nq = fmax(sqrt(x2q), 1e-15);
    double aq = atanh(fmin(nq, 1.0 - 1e-7)) / nq;
    double nc = fmax(sqrt(x2c), 1e-15);
    double ac = atanh(fmin(nc, 1.0 - 1e-7)) / nc;
    double f = aq * xq[tid] - ac * xc[tid];
    double n2 = blockSum(f * f, red, tid);
    double fb = f / fmax(sqrt(n2), 1e-8);
    wproj = (variance > 1e-5) ? wg : fb;
  }

  // ---- h_comp, x, pitchfork RK4 ----
  double hn2 = blockSum(hreg * hreg, red, tid);
  double hn = sqrt(hn2);
  double hsc = asinh(hn) / (hn + 1e-8);
  double hc = hsc * hreg;
  double x = blockSum(hc * wproj, red, tid);
  double xi = (x == 0.0) ? odeval : x;
  const double dt = 0.5;
#pragma unroll
  for (int r = 0; r < 4; ++r) {
    double k1 = dt * (tension * xi - xi * xi * xi);
    double a2 = xi + 0.5 * k1;
    double k2 = dt * (tension * a2 - a2 * a2 * a2);
    double a3 = xi + 0.5 * k2;
    double k3 = dt * (tension * a3 - a3 * a3 * a3);
    double a4 = xi + k3;
    double k4 = dt * (tension * a4 - a4 * a4 * a4);
    xi += (k1 + 2.0 * k2 + 2.0 * k3 + k4) / 6.0;
  }
  double ts = (double)ts_p[0];
  double hp = (hc + (xi - x) * wproj) * ts;
  double hp2 = blockSum(hp * hp, red, tid);
  double nhp = sqrt(hp2);
  double cf = fmin(4.0 / (nhp + 1e-8), 1.0);
  double ncl = fmax(nhp * cf, 1e-15);
  double th = tanh(ncl);
  double nb = fmax(th, 1e-15);
  double ab = atanh(fmin(nb, 1.0 - 1e-7)) / nb;
  double hob = ab * th * cf / ncl * hp;
  double gate = fmax(tanh(tension / fmax(tau, 1e-3)), 0.0);
  hfused[rowOff + tid] = (float)((1.0 - gate) * hreg + gate * hob);
}

// ---------------- launch ----------------
extern "C" void kernel_launch(void* const* d_in, const int* in_sizes, int n_in,
                              void* d_out, int out_size, void* d_ws, size_t ws_size,
                              hipStream_t stream) {
  const float* q_in = (const float*)d_in[0];
  const float* k_in = (const float*)d_in[1];
  const float* v_in = (const float*)d_in[2];
  const float* Wq = (const float*)d_in[3];
  const float* bq = (const float*)d_in[4];
  const float* Wk = (const float*)d_in[5];
  const float* bk = (const float*)d_in[6];
  const float* Wv = (const float*)d_in[7];
  const float* bv = (const float*)d_in[8];
  const float* Wo = (const float*)d_in[9];
  const float* bo = (const float*)d_in[10];
  const float* tau = (const float*)d_in[11];
  const float* ts = (const float*)d_in[12];
  float* out = (float*)d_out;
  (void)in_sizes; (void)n_in; (void)out_size; (void)ws_size;

  char* base = (char*)d_ws;
  size_t off = 0;
  auto alloc = [&](size_t bytes) -> void* {
    void* p = base + off;
    off += (bytes + 255) & ~(size_t)255;
    return p;
  };
  float* WqT = (float*)alloc((size_t)DD * DD * 4);
  float* WkT = (float*)alloc((size_t)DD * DD * 4);
  float* WvT = (float*)alloc((size_t)DD * DD * 4);
  float* WoT = (float*)alloc((size_t)DD * DD * 4);
  float* kb = (float*)alloc((size_t)NE * 4);
  float* vb = (float*)alloc((size_t)NE * 4);
  float* qh = (float*)alloc((size_t)NE * 4);
  float* kh = (float*)alloc((size_t)NE * 4);
  float* khT = (float*)alloc((size_t)NE * 4);
  double* y2g = (double*)alloc((size_t)NROW * 8);
  float* hf = (float*)alloc((size_t)NE * 4);

  hipLaunchKernelGGL(transpose4, dim3(4 * DD), dim3(DD), 0, stream,
                     Wq, Wk, Wv, Wo, WqT, WkT, WvT, WoT);
  hipLaunchKernelGGL(proj_kernel, dim3(NROW, 3), dim3(DD), 0, stream,
                     q_in, k_in, v_in, WqT, WkT, WvT, bq, bk, bv,
                     qh, kb, vb, kh, khT, y2g);
  hipLaunchKernelGGL(resonance_main, dim3(NROW), dim3(DD), 0, stream,
                     qh, kh, khT, kb, vb, y2g, tau, ts, hf);
  hipLaunchKernelGGL(gemm_out, dim3(NROW), dim3(DD), 0, stream, hf, WoT, bo, out);
}